// Round 3
// baseline (1660.892 us; speedup 1.0000x reference)
//
#include <hip/hip_runtime.h>
#include <hip/hip_fp16.h>
#include <cstddef>
#include <cstdint>

#define NB 8
#define NR 128
#define C0 1024
#define FM 19
#define NPOS 49
#define C1 256
#define C2 256
#define C3 32
#define EPSV 1e-5f

// d_out (fp32 elements): er_c [8,1,128,4] | out_c [8,128,32,7,7] | keep_count [8]
#define OUT_OC   4096
#define OUT_KEEP 1609728   // 4096 + 8*128*32*49

// workspace layout (bytes). total ~75 MB (proven sufficient: round-2 conv3 values landed in out)
static constexpr size_t OFF_META = 256;                                    // 1024 * 8 ints
static constexpr size_t OFF_FT   = OFF_META + (size_t)1024 * 8 * 4;        // feat transposed [8][361][1024] f32
static constexpr size_t OFF_W1   = OFF_FT + (size_t)NB * 361 * C0 * 4;     // [9216][256] f32
static constexpr size_t OFF_W2   = OFF_W1 + (size_t)C0 * 9 * C1 * 4;       // [2304][256] f32
static constexpr size_t OFF_W3   = OFF_W2 + (size_t)C1 * 9 * C2 * 4;       // [256][32] f32
static constexpr size_t OFF_X1   = OFF_W3 + (size_t)C2 * C3 * 4;           // [1024][256][49] f16
static constexpr size_t OFF_X2   = OFF_X1 + (size_t)1024 * C1 * NPOS * 2;  // [1024][256][49] f16
static constexpr size_t WS_NEED  = OFF_X2 + (size_t)1024 * C2 * NPOS * 2;

// ---------------- setup: ROI decode, validity, stable compaction, er_c, keep_count
__global__ void k_setup(const float* __restrict__ roi, int* __restrict__ cnt,
                        int* __restrict__ meta, float* __restrict__ out)
{
  int b = blockIdx.x, t = threadIdx.x;            // 8 blocks x 128 threads
  __shared__ int sval[128], spre[129];
  const float* rp = roi + (size_t)(b * NR + t) * 5;
  int rl[4], cl[4];
#pragma unroll
  for (int j = 0; j < 4; ++j) {
    rl[j] = (int)(rp[1 + j] * 18.75f);            // trunc toward zero, matches astype(int32)
    cl[j] = min(max(rl[j], 0), 18);
  }
  int valid = (cl[2] > cl[0]) && (cl[3] > cl[1]) ? 1 : 0;
  sval[t] = valid;
  __syncthreads();
  if (t == 0) {
    int s = 0;
    for (int i = 0; i < 128; ++i) { spre[i] = s; s += sval[i]; }
    spre[128] = s;
    out[OUT_KEEP + b] = (float)s;                 // keep_count (compared as float)
  }
  __syncthreads();
  if (valid) {
    int dst = spre[t];
    int slot = atomicAdd(cnt, 1);
    int* mt = meta + slot * 8;
    mt[0] = b; mt[1] = dst;
    mt[2] = cl[1]; mt[3] = cl[3];                 // ylo, yhi
    mt[4] = cl[0]; mt[5] = cl[2];                 // xlo, xhi
#pragma unroll
    for (int j = 0; j < 4; ++j)                   // er uses UNclamped rl (ref semantics)
      out[(size_t)(b * NR + dst) * 4 + j] = (float)rl[j] * (16.0f / 300.0f);
  }
}

// ---------------- packs (run every launch; ws is re-poisoned each call)
__global__ void k_pack_feat(const float* __restrict__ in, float* __restrict__ ft) {
  int i = blockIdx.x * 256 + threadIdx.x;         // [8][1024][361] -> [8][361][1024] f32
  if (i >= NB * C0 * FM * FM) return;
  int hw = i % 361; int tmp = i / 361; int c = tmp % C0; int b = tmp / C0;
  ft[(size_t)(b * 361 + hw) * C0 + c] = in[i];
}
__global__ void k_pack_w(const float* __restrict__ in, float* __restrict__ wp, int OC, int ICK) {
  int i = blockIdx.x * 256 + threadIdx.x;         // [OC][ICK] -> [ICK][OC] f32
  if (i >= OC * ICK) return;
  int oc = i / ICK, ick = i - oc * ICK;
  wp[(size_t)ick * OC + oc] = in[i];
}

// ---------------- shared conv core: 64 input channels, 3x3, 16 oc per thread (wave-uniform)
__device__ __forceinline__ void conv_accum64(const float (*tile)[81],
                                             const float* __restrict__ wbase,
                                             int py, int px, float* acc)
{
  for (int ic = 0; ic < 64; ++ic) {
    const float* wr = wbase + (size_t)ic * (9 * 256);
#pragma unroll
    for (int k = 0; k < 9; ++k) {
      float xv = tile[ic][(py + k / 3) * 9 + (px + k - (k / 3) * 3)];
      const float4* w4 = (const float4*)(wr + k * 256);
      float4 wa = w4[0], wb = w4[1], wc = w4[2], wd = w4[3];
      acc[0]  = fmaf(xv, wa.x, acc[0]);  acc[1]  = fmaf(xv, wa.y, acc[1]);
      acc[2]  = fmaf(xv, wa.z, acc[2]);  acc[3]  = fmaf(xv, wa.w, acc[3]);
      acc[4]  = fmaf(xv, wb.x, acc[4]);  acc[5]  = fmaf(xv, wb.y, acc[5]);
      acc[6]  = fmaf(xv, wb.z, acc[6]);  acc[7]  = fmaf(xv, wb.w, acc[7]);
      acc[8]  = fmaf(xv, wc.x, acc[8]);  acc[9]  = fmaf(xv, wc.y, acc[9]);
      acc[10] = fmaf(xv, wc.z, acc[10]); acc[11] = fmaf(xv, wc.w, acc[11]);
      acc[12] = fmaf(xv, wd.x, acc[12]); acc[13] = fmaf(xv, wd.y, acc[13]);
      acc[14] = fmaf(xv, wd.z, acc[14]); acc[15] = fmaf(xv, wd.w, acc[15]);
    }
  }
}

// ---------------- fused adaptive-pool + conv1 + BN + ReLU -> x1 (f16)
__global__ __launch_bounds__(256) void k_conv1(
    const int* __restrict__ cnt, const int* __restrict__ meta,
    const float* __restrict__ ft, const float* __restrict__ wp1,
    const float* __restrict__ bb, const float* __restrict__ gg, const float* __restrict__ bec,
    const float* __restrict__ mm, const float* __restrict__ vv,
    __half* __restrict__ x1)
{
  int slot = blockIdx.x;
  if (slot >= *cnt) return;
  const int* mt = meta + slot * 8;
  int b = mt[0], ylo = mt[2], yhi = mt[3], xlo = mt[4], xhi = mt[5];
  int Hy = yhi - ylo + 1, Hx = xhi - xlo + 1;
  __shared__ float tile[64][81];                  // padded 9x9 per channel, border stays 0
  int tid = threadIdx.x;
  for (int i = tid; i < 64 * 81; i += 256) (&tile[0][0])[i] = 0.f;
  __syncthreads();
  int lane = tid & 63, wv = tid >> 6;
  int ocbase = __builtin_amdgcn_readfirstlane((int)blockIdx.y * 64 + wv * 16);
  int pos = lane < NPOS ? lane : 0;
  int py = pos / 7, px = pos - py * 7;
  float acc[16];
#pragma unroll
  for (int j = 0; j < 16; ++j) acc[j] = 0.f;

  for (int ct = 0; ct < 16; ++ct) {
    // adaptive-avg-pool 64 channels x 49 bins into LDS (coalesced on channel)
    for (int task = tid; task < 64 * NPOS; task += 256) {
      int ch = task & 63, bin = task >> 6;
      int p = bin / 7, q = bin - p * 7;
      int sy = (p * Hy) / 7, ey = ((p + 1) * Hy + 6) / 7;
      int sx = (q * Hx) / 7, ex = ((q + 1) * Hx + 6) / 7;
      float s = 0.f;
      for (int h = ylo + sy; h < ylo + ey; ++h)
        for (int w = xlo + sx; w < xlo + ex; ++w)
          s += ft[(size_t)(b * 361 + h * 19 + w) * C0 + ct * 64 + ch];
      tile[ch][(p + 1) * 9 + q + 1] = s / (float)((ey - sy) * (ex - sx));
    }
    __syncthreads();
    conv_accum64(tile, wp1 + (size_t)(ct * 64) * 9 * 256 + ocbase, py, px, acc);
    __syncthreads();
  }
  if (lane < NPOS) {
#pragma unroll
    for (int j = 0; j < 16; ++j) {
      int oc = ocbase + j;
      float sc = gg[oc] * rsqrtf(vv[oc] + EPSV);
      float sh = (bb[oc] - mm[oc]) * sc + bec[oc];    // fold conv bias into BN shift
      float y = fmaf(acc[j], sc, sh);
      x1[((size_t)slot * C1 + oc) * NPOS + pos] = __float2half(y > 0.f ? y : 0.f);
    }
  }
}

// ---------------- conv2 + BN + ReLU -> x2 (f16)
__global__ __launch_bounds__(256) void k_conv2(
    const int* __restrict__ cnt, const int* __restrict__ meta,
    const __half* __restrict__ x1, const float* __restrict__ wp2,
    const float* __restrict__ bb, const float* __restrict__ gg, const float* __restrict__ bec,
    const float* __restrict__ mm, const float* __restrict__ vv,
    __half* __restrict__ x2)
{
  int slot = blockIdx.x;
  if (slot >= *cnt) return;
  __shared__ float tile[64][81];
  int tid = threadIdx.x;
  for (int i = tid; i < 64 * 81; i += 256) (&tile[0][0])[i] = 0.f;
  __syncthreads();
  int lane = tid & 63, wv = tid >> 6;
  int ocbase = __builtin_amdgcn_readfirstlane((int)blockIdx.y * 64 + wv * 16);
  int pos = lane < NPOS ? lane : 0;
  int py = pos / 7, px = pos - py * 7;
  float acc[16];
#pragma unroll
  for (int j = 0; j < 16; ++j) acc[j] = 0.f;

  for (int ct = 0; ct < 4; ++ct) {
    for (int task = tid; task < 64 * NPOS; task += 256) {
      int ch = task / NPOS, p = task - ch * NPOS;
      int pr = p / 7, pc = p - pr * 7;
      tile[ch][(pr + 1) * 9 + pc + 1] = __half2float(x1[((size_t)slot * C1 + ct * 64 + ch) * NPOS + p]);
    }
    __syncthreads();
    conv_accum64(tile, wp2 + (size_t)(ct * 64) * 9 * 256 + ocbase, py, px, acc);
    __syncthreads();
  }
  if (lane < NPOS) {
#pragma unroll
    for (int j = 0; j < 16; ++j) {
      int oc = ocbase + j;
      float sc = gg[oc] * rsqrtf(vv[oc] + EPSV);
      float sh = (bb[oc] - mm[oc]) * sc + bec[oc];
      float y = fmaf(acc[j], sc, sh);
      x2[((size_t)slot * C2 + oc) * NPOS + pos] = __float2half(y > 0.f ? y : 0.f);
    }
  }
}

// ---------------- conv3 (1x1) + BN + ReLU + scatter to compacted out_c
__global__ __launch_bounds__(256) void k_conv3(
    const int* __restrict__ cnt, const int* __restrict__ meta,
    const __half* __restrict__ x2, const float* __restrict__ wp3,
    const float* __restrict__ gg, const float* __restrict__ bec,
    const float* __restrict__ mm, const float* __restrict__ vv,
    float* __restrict__ out)
{
  int slot = blockIdx.x;
  if (slot >= *cnt) return;
  const int* mt = meta + slot * 8;
  int b = mt[0], dst = mt[1];
  __shared__ float t3[C2 * NPOS];                 // 50 KB
  int tid = threadIdx.x;
  for (int i = tid; i < C2 * NPOS; i += 256) t3[i] = __half2float(x2[(size_t)slot * C2 * NPOS + i]);
  __syncthreads();
  int oc = tid & 31, pg = tid >> 5;               // 32 oc x 8 position groups
  float acc[7];
#pragma unroll
  for (int j = 0; j < 7; ++j) acc[j] = 0.f;
  for (int ic = 0; ic < C2; ++ic) {
    float w = wp3[ic * 32 + oc];
#pragma unroll
    for (int j = 0; j < 7; ++j) {
      int p = pg + j * 8;
      if (p < NPOS) acc[j] = fmaf(t3[ic * NPOS + p], w, acc[j]);
    }
  }
  float sc = gg[oc] * rsqrtf(vv[oc] + EPSV);
  float sh = bec[oc] - mm[oc] * sc;               // no conv bias for layer 3
  size_t obase = OUT_OC + ((size_t)(b * NR + dst) * C3 + oc) * NPOS;
#pragma unroll
  for (int j = 0; j < 7; ++j) {
    int p = pg + j * 8;
    if (p < NPOS) {
      float y = fmaf(acc[j], sc, sh);
      out[obase + p] = y > 0.f ? y : 0.f;
    }
  }
}

extern "C" void kernel_launch(void* const* d_in, const int* in_sizes, int n_in,
                              void* d_out, int out_size, void* d_ws, size_t ws_size,
                              hipStream_t stream)
{
  (void)in_sizes; (void)n_in;
  if (ws_size < WS_NEED) return;  // would corrupt; fail loudly as all-zero output

  const float* roi  = (const float*)d_in[0];
  const float* feat = (const float*)d_in[1];
  const float* W1   = (const float*)d_in[2];
  const float* b1   = (const float*)d_in[3];
  const float* g1   = (const float*)d_in[4];
  const float* be1  = (const float*)d_in[5];
  const float* m1   = (const float*)d_in[6];
  const float* v1   = (const float*)d_in[7];
  const float* W2   = (const float*)d_in[8];
  const float* b2   = (const float*)d_in[9];
  const float* g2   = (const float*)d_in[10];
  const float* be2  = (const float*)d_in[11];
  const float* m2   = (const float*)d_in[12];
  const float* v2   = (const float*)d_in[13];
  const float* W3   = (const float*)d_in[14];
  const float* g3   = (const float*)d_in[15];
  const float* be3  = (const float*)d_in[16];
  const float* m3   = (const float*)d_in[17];
  const float* v3   = (const float*)d_in[18];

  char* ws   = (char*)d_ws;
  int*  cnt  = (int*)ws;
  int*  meta = (int*)(ws + OFF_META);
  float* ft  = (float*)(ws + OFF_FT);
  float* wp1 = (float*)(ws + OFF_W1);
  float* wp2 = (float*)(ws + OFF_W2);
  float* wp3 = (float*)(ws + OFF_W3);
  __half* x1 = (__half*)(ws + OFF_X1);
  __half* x2 = (__half*)(ws + OFF_X2);
  float* out = (float*)d_out;

  hipMemsetAsync(cnt, 0, 4, stream);
  hipMemsetAsync(d_out, 0, (size_t)out_size * sizeof(float), stream);

  k_pack_feat<<<(NB * C0 * FM * FM + 255) / 256, 256, 0, stream>>>(feat, ft);
  k_pack_w<<<(C1 * C0 * 9 + 255) / 256, 256, 0, stream>>>(W1, wp1, C1, C0 * 9);
  k_pack_w<<<(C2 * C1 * 9 + 255) / 256, 256, 0, stream>>>(W2, wp2, C2, C1 * 9);
  k_pack_w<<<(C3 * C2 + 255) / 256, 256, 0, stream>>>(W3, wp3, C3, C2);
  k_setup<<<NB, NR, 0, stream>>>(roi, cnt, meta, out);

  k_conv1<<<dim3(NB * NR, 4), 256, 0, stream>>>(cnt, meta, ft, wp1, b1, g1, be1, m1, v1, x1);
  k_conv2<<<dim3(NB * NR, 4), 256, 0, stream>>>(cnt, meta, x1, wp2, b2, g2, be2, m2, v2, x2);
  k_conv3<<<NB * NR, 256, 0, stream>>>(cnt, meta, x2, wp3, g3, be3, m3, v3, out);
}

// Round 4
// 764.273 us; speedup vs baseline: 2.1732x; 2.1732x over previous
//
#include <hip/hip_runtime.h>
#include <cstddef>
#include <cstdint>

typedef unsigned short u16;
typedef __attribute__((ext_vector_type(8))) short short8;   // 8 bf16 (4 VGPRs)
typedef __attribute__((ext_vector_type(4))) float f32x4;    // 4 fp32 acc

#define NB 8
#define NR 128
#define C0 1024
#define FM 19
#define NPOS 49
#define C1 256
#define C2 256
#define C3 32
#define EPSV 1e-5f

// d_out (fp32): er_c [8,1,128,4] | out_c [8,128,32,7,7] | keep_count [8]
#define OUT_OC   4096
#define OUT_KEEP 1609728

// workspace layout (bytes), total 57,344,256 < proven-available ~75 MB
static constexpr size_t OFF_META = 256;                       // cnt at 0
static constexpr size_t OFF_W1Q  = OFF_META + 32768;          // bf16 frag-packed W1: 16c*18kk*16nt*64lane*8
static constexpr size_t OFF_W2Q  = OFF_W1Q + 4718592;
static constexpr size_t OFF_W3   = OFF_W2Q + 1179648;         // f32 [256 ic][32 oc]
static constexpr size_t OFF_X1   = OFF_W3  + 32768;           // bf16 [1024 slot][4 c][49 pos][64]
static constexpr size_t OFF_SH   = OFF_X1  + 25690112;        // ft f32 [8][361][1024] (conv1), then x2 bf16 [1024][49][256] (conv2/3)
static constexpr size_t WS_NEED  = OFF_SH  + 25690112;

static __device__ __forceinline__ float bf2f(u16 v) {
  union { unsigned int u; float f; } x; x.u = ((unsigned int)v) << 16; return x.f;
}
static __device__ __forceinline__ u16 f2bf(float f) {
  union { float f; unsigned int u; } x; x.f = f;
  unsigned int r = 0x7fffu + ((x.u >> 16) & 1u);
  return (u16)((x.u + r) >> 16);
}

// ---------------- setup: ROI decode, validity, stable compaction, er_c, keep_count
__global__ void k_setup(const float* __restrict__ roi, int* __restrict__ cnt,
                        int* __restrict__ meta, float* __restrict__ out)
{
  int b = blockIdx.x, t = threadIdx.x;
  __shared__ int sval[128], spre[129];
  const float* rp = roi + (size_t)(b * NR + t) * 5;
  int rl[4], cl[4];
#pragma unroll
  for (int j = 0; j < 4; ++j) {
    rl[j] = (int)(rp[1 + j] * 18.75f);
    cl[j] = min(max(rl[j], 0), 18);
  }
  int valid = (cl[2] > cl[0]) && (cl[3] > cl[1]) ? 1 : 0;
  sval[t] = valid;
  __syncthreads();
  if (t == 0) {
    int s = 0;
    for (int i = 0; i < 128; ++i) { spre[i] = s; s += sval[i]; }
    out[OUT_KEEP + b] = (float)s;
  }
  __syncthreads();
  if (valid) {
    int dst = spre[t];
    int slot = atomicAdd(cnt, 1);
    int* mt = meta + slot * 8;
    mt[0] = b; mt[1] = dst;
    mt[2] = cl[1]; mt[3] = cl[3];
    mt[4] = cl[0]; mt[5] = cl[2];
#pragma unroll
    for (int j = 0; j < 4; ++j)
      out[(size_t)(b * NR + dst) * 4 + j] = (float)rl[j] * (16.0f / 300.0f);
  }
}

// ---------------- LDS-tiled transpose: feat [8][1024][361] f32 -> ft [8][361][1024] f32
__global__ void k_tr(const float* __restrict__ in, float* __restrict__ ft) {
  int b = blockIdx.x, hw0 = blockIdx.y * 64, c0 = blockIdx.z * 64;
  __shared__ float T[64][65];
  int tx = threadIdx.x & 63, ty = threadIdx.x >> 6;
#pragma unroll
  for (int i = 0; i < 16; ++i) {
    int r = ty + i * 4, hw = hw0 + tx;
    T[r][tx] = (hw < 361) ? in[((size_t)b * 1024 + c0 + r) * 361 + hw] : 0.f;
  }
  __syncthreads();
#pragma unroll
  for (int i = 0; i < 16; ++i) {
    int r = ty + i * 4, hw = hw0 + r;
    if (hw < 361) ft[((size_t)b * 361 + hw) * 1024 + c0 + tx] = T[tx][r];
  }
}

// ---------------- pack 3x3 conv weights (fp32 OIHW) into bf16 MFMA-fragment order:
// dst[(c*18 + k9i*2 + ks)][nt16][lane][8]  where oc = nt16*16 + (lane&15),
// ic = c*64 + ks*32 + (lane>>4)*8 + j, tap (ky,kx) = (k9i/3, k9i%3).
__global__ void k_pack_wq(const float* __restrict__ W, u16* __restrict__ wq, int IC) {
  int bid = blockIdx.x;                 // (c*9 + k9i)*2 + ks
  int ks = bid & 1, t2 = bid >> 1;
  int k9i = t2 % 9, c = t2 / 9;
  int ky = k9i / 3, kx = k9i - 3 * ky;
  int tid = threadIdx.x;                // 1024 = nt16*64 + lane
  int lane = tid & 63, nt16 = tid >> 6;
  int oc = nt16 * 16 + (lane & 15);
  int icb = c * 64 + ks * 32 + (lane >> 4) * 8;
  u16 v[8];
#pragma unroll
  for (int j = 0; j < 8; ++j)
    v[j] = f2bf(W[(((size_t)oc * IC + icb + j) * 3 + ky) * 3 + kx]);
  *(uint4*)(wq + ((size_t)bid * 1024 + tid) * 8) = *(uint4*)v;
}

__global__ void k_pack_w3(const float* __restrict__ in, float* __restrict__ wp) {
  int i = blockIdx.x * 256 + threadIdx.x;   // [32 oc][256 ic] -> [ic][oc]
  if (i >= C3 * C2) return;
  int oc = i / C2, ic = i - oc * C2;
  wp[ic * C3 + oc] = in[i];
}

// ---------------- conv1: fused adaptive-pool (bf16 LDS tile) + MFMA GEMM + BN + ReLU -> x1
__global__ __launch_bounds__(256) void k_conv1(
    const int* __restrict__ cnt, const int* __restrict__ meta,
    const float* __restrict__ ft, const u16* __restrict__ w1q,
    const float* __restrict__ bb, const float* __restrict__ gg, const float* __restrict__ bec,
    const float* __restrict__ mm, const float* __restrict__ vv,
    u16* __restrict__ x1g)
{
  int slot = blockIdx.x;
  if (slot >= *cnt) return;
  const int* mt_ = meta + slot * 8;
  int b = mt_[0], ylo = mt_[2], yhi = mt_[3], xlo = mt_[4], xhi = mt_[5];
  int Hy = yhi - ylo + 1, Hx = xhi - xlo + 1;

  __shared__ __align__(16) u16 At[82 * 72];   // padded 9x9 grid rows (stride 72 bf16), row 81 = zero
  int tid = threadIdx.x;
  for (int i = tid; i < 82 * 72 / 2; i += 256) ((unsigned int*)At)[i] = 0;

  int lane = tid & 63, w = tid >> 6;
  int n = lane & 15, kq = lane >> 4;
  int rowb[4];
#pragma unroll
  for (int mt = 0; mt < 4; ++mt) {
    int m = mt * 16 + n;
    rowb[mt] = (m < 49) ? ((m / 7) * 9 + (m % 7)) : -1;
  }
  f32x4 acc[4][4];
#pragma unroll
  for (int i = 0; i < 4; ++i)
#pragma unroll
    for (int j = 0; j < 4; ++j) acc[i][j] = (f32x4){0.f, 0.f, 0.f, 0.f};
  __syncthreads();

  for (int c = 0; c < 16; ++c) {
    // pool 64 channels x 49 bins into interior of At (bf16)
    for (int t = tid; t < 64 * 49; t += 256) {
      int ch = t & 63, bin = t >> 6;
      int p = bin / 7, q = bin - p * 7;
      int sy = (p * Hy) / 7, ey = ((p + 1) * Hy + 6) / 7;
      int sx = (q * Hx) / 7, ex = ((q + 1) * Hx + 6) / 7;
      float s = 0.f;
      for (int h = ylo + sy; h < ylo + ey; ++h)
        for (int x = xlo + sx; x < xlo + ex; ++x)
          s += ft[(size_t)(b * 361 + h * 19 + x) * 1024 + c * 64 + ch];
      s /= (float)((ey - sy) * (ex - sx));
      At[((p + 1) * 9 + (q + 1)) * 72 + ch] = f2bf(s);
    }
    __syncthreads();
#pragma unroll
    for (int kk = 0; kk < 18; ++kk) {
      int k9i = kk >> 1, ks = kk & 1;
      int shift = k9i + 6 * (k9i / 3);      // = ky*9 + kx
      short8 bfr[4], afr[4];
#pragma unroll
      for (int nt = 0; nt < 4; ++nt)
        bfr[nt] = *(const short8*)(w1q + ((size_t)((c * 18 + kk) * 16 + (w * 4 + nt)) * 512 + lane * 8));
#pragma unroll
      for (int mt = 0; mt < 4; ++mt) {
        int r0 = rowb[mt];
        int rr = (r0 < 0) ? 81 : r0 + shift;
        afr[mt] = *(const short8*)(At + rr * 72 + ks * 32 + kq * 8);
      }
#pragma unroll
      for (int mt = 0; mt < 4; ++mt)
#pragma unroll
        for (int nt = 0; nt < 4; ++nt)
          acc[mt][nt] = __builtin_amdgcn_mfma_f32_16x16x32_bf16(afr[mt], bfr[nt], acc[mt][nt], 0, 0, 0);
    }
    __syncthreads();
  }
  // epilogue: BN + ReLU -> x1g[slot][oc>>6][m][oc&63] bf16
#pragma unroll
  for (int nt = 0; nt < 4; ++nt) {
    int oc = (w * 4 + nt) * 16 + n;
    float sc = gg[oc] * rsqrtf(vv[oc] + EPSV);
    float sh = (bb[oc] - mm[oc]) * sc + bec[oc];
#pragma unroll
    for (int mt = 0; mt < 4; ++mt)
#pragma unroll
      for (int r = 0; r < 4; ++r) {
        int m = mt * 16 + kq * 4 + r;
        if (m < 49) {
          float y = fmaf(acc[mt][nt][r], sc, sh);
          x1g[((size_t)(slot * 4 + w) * 49 + m) * 64 + nt * 16 + n] = f2bf(y > 0.f ? y : 0.f);
        }
      }
  }
}

// ---------------- conv2: A staged from x1g (bf16) + MFMA + BN + ReLU -> x2 [slot][49][256]
__global__ __launch_bounds__(256) void k_conv2(
    const int* __restrict__ cnt,
    const u16* __restrict__ x1g, const u16* __restrict__ w2q,
    const float* __restrict__ bb, const float* __restrict__ gg, const float* __restrict__ bec,
    const float* __restrict__ mm, const float* __restrict__ vv,
    u16* __restrict__ x2)
{
  int slot = blockIdx.x;
  if (slot >= *cnt) return;
  __shared__ __align__(16) u16 At[82 * 72];
  int tid = threadIdx.x;
  for (int i = tid; i < 82 * 72 / 2; i += 256) ((unsigned int*)At)[i] = 0;

  int lane = tid & 63, w = tid >> 6;
  int n = lane & 15, kq = lane >> 4;
  int rowb[4];
#pragma unroll
  for (int mt = 0; mt < 4; ++mt) {
    int m = mt * 16 + n;
    rowb[mt] = (m < 49) ? ((m / 7) * 9 + (m % 7)) : -1;
  }
  f32x4 acc[4][4];
#pragma unroll
  for (int i = 0; i < 4; ++i)
#pragma unroll
    for (int j = 0; j < 4; ++j) acc[i][j] = (f32x4){0.f, 0.f, 0.f, 0.f};
  __syncthreads();

  for (int c = 0; c < 4; ++c) {
    // stage [81 rows][64 ic] from x1g, zeroing border rows
    for (int idx = tid; idx < 81 * 8; idx += 256) {
      int row = idx >> 3, j = idx & 7;
      int gy = row / 9, gx = row - gy * 9;
      uint4 v = {0u, 0u, 0u, 0u};
      if (gy >= 1 && gy <= 7 && gx >= 1 && gx <= 7)
        v = *(const uint4*)(x1g + ((size_t)(slot * 4 + c) * 49 + (gy - 1) * 7 + (gx - 1)) * 64 + j * 8);
      *(uint4*)(&At[row * 72 + j * 8]) = v;
    }
    __syncthreads();
#pragma unroll
    for (int kk = 0; kk < 18; ++kk) {
      int k9i = kk >> 1, ks = kk & 1;
      int shift = k9i + 6 * (k9i / 3);
      short8 bfr[4], afr[4];
#pragma unroll
      for (int nt = 0; nt < 4; ++nt)
        bfr[nt] = *(const short8*)(w2q + ((size_t)((c * 18 + kk) * 16 + (w * 4 + nt)) * 512 + lane * 8));
#pragma unroll
      for (int mt = 0; mt < 4; ++mt) {
        int r0 = rowb[mt];
        int rr = (r0 < 0) ? 81 : r0 + shift;
        afr[mt] = *(const short8*)(At + rr * 72 + ks * 32 + kq * 8);
      }
#pragma unroll
      for (int mt = 0; mt < 4; ++mt)
#pragma unroll
        for (int nt = 0; nt < 4; ++nt)
          acc[mt][nt] = __builtin_amdgcn_mfma_f32_16x16x32_bf16(afr[mt], bfr[nt], acc[mt][nt], 0, 0, 0);
    }
    __syncthreads();
  }
#pragma unroll
  for (int nt = 0; nt < 4; ++nt) {
    int oc = (w * 4 + nt) * 16 + n;
    float sc = gg[oc] * rsqrtf(vv[oc] + EPSV);
    float sh = (bb[oc] - mm[oc]) * sc + bec[oc];
#pragma unroll
    for (int mt = 0; mt < 4; ++mt)
#pragma unroll
      for (int r = 0; r < 4; ++r) {
        int m = mt * 16 + kq * 4 + r;
        if (m < 49) {
          float y = fmaf(acc[mt][nt][r], sc, sh);
          x2[((size_t)slot * 49 + m) * 256 + oc] = f2bf(y > 0.f ? y : 0.f);
        }
      }
  }
}

// ---------------- conv3 (1x1) + BN + ReLU + scatter to compacted out_c
__global__ __launch_bounds__(256) void k_conv3(
    const int* __restrict__ cnt, const int* __restrict__ meta,
    const u16* __restrict__ x2, const float* __restrict__ wp3,
    const float* __restrict__ gg, const float* __restrict__ bec,
    const float* __restrict__ mm, const float* __restrict__ vv,
    float* __restrict__ out)
{
  int slot = blockIdx.x;
  if (slot >= *cnt) return;
  const int* mt = meta + slot * 8;
  int b = mt[0], dst = mt[1];
  __shared__ float t3[NPOS * C2];               // [pos][ic], 50 KB
  int tid = threadIdx.x;
  for (int i = tid; i < NPOS * C2; i += 256) t3[i] = bf2f(x2[(size_t)slot * NPOS * C2 + i]);
  __syncthreads();
  int oc = tid & 31, pg = tid >> 5;
  float acc[7];
#pragma unroll
  for (int j = 0; j < 7; ++j) acc[j] = 0.f;
  for (int ic = 0; ic < C2; ++ic) {
    float wv = wp3[ic * 32 + oc];
#pragma unroll
    for (int j = 0; j < 7; ++j) {
      int p = pg + j * 8;
      if (p < NPOS) acc[j] = fmaf(t3[p * C2 + ic], wv, acc[j]);
    }
  }
  float sc = gg[oc] * rsqrtf(vv[oc] + EPSV);
  float sh = bec[oc] - mm[oc] * sc;
  size_t obase = OUT_OC + ((size_t)(b * NR + dst) * C3 + oc) * NPOS;
#pragma unroll
  for (int j = 0; j < 7; ++j) {
    int p = pg + j * 8;
    if (p < NPOS) {
      float y = fmaf(acc[j], sc, sh);
      out[obase + p] = y > 0.f ? y : 0.f;
    }
  }
}

extern "C" void kernel_launch(void* const* d_in, const int* in_sizes, int n_in,
                              void* d_out, int out_size, void* d_ws, size_t ws_size,
                              hipStream_t stream)
{
  (void)in_sizes; (void)n_in;
  if (ws_size < WS_NEED) return;

  const float* roi  = (const float*)d_in[0];
  const float* feat = (const float*)d_in[1];
  const float* W1   = (const float*)d_in[2];
  const float* b1   = (const float*)d_in[3];
  const float* g1   = (const float*)d_in[4];
  const float* be1  = (const float*)d_in[5];
  const float* m1   = (const float*)d_in[6];
  const float* v1   = (const float*)d_in[7];
  const float* W2   = (const float*)d_in[8];
  const float* b2   = (const float*)d_in[9];
  const float* g2   = (const float*)d_in[10];
  const float* be2  = (const float*)d_in[11];
  const float* m2   = (const float*)d_in[12];
  const float* v2   = (const float*)d_in[13];
  const float* W3   = (const float*)d_in[14];
  const float* g3   = (const float*)d_in[15];
  const float* be3  = (const float*)d_in[16];
  const float* m3   = (const float*)d_in[17];
  const float* v3   = (const float*)d_in[18];

  char* ws   = (char*)d_ws;
  int*  cnt  = (int*)ws;
  int*  meta = (int*)(ws + OFF_META);
  u16*  w1q  = (u16*)(ws + OFF_W1Q);
  u16*  w2q  = (u16*)(ws + OFF_W2Q);
  float* wp3 = (float*)(ws + OFF_W3);
  u16*  x1g  = (u16*)(ws + OFF_X1);
  float* ft  = (float*)(ws + OFF_SH);   // conv1 input (transposed features)
  u16*  x2   = (u16*)(ws + OFF_SH);     // aliases ft: ft dead after k_conv1, kernels serialize on stream
  float* out = (float*)d_out;

  hipMemsetAsync(cnt, 0, 4, stream);
  hipMemsetAsync(d_out, 0, (size_t)out_size * sizeof(float), stream);

  k_tr<<<dim3(NB, 6, 16), 256, 0, stream>>>(feat, ft);
  k_pack_wq<<<16 * 9 * 2, 1024, 0, stream>>>(W1, w1q, 1024);
  k_pack_wq<<<4 * 9 * 2, 1024, 0, stream>>>(W2, w2q, 256);
  k_pack_w3<<<(C3 * C2 + 255) / 256, 256, 0, stream>>>(W3, wp3);
  k_setup<<<NB, NR, 0, stream>>>(roi, cnt, meta, out);

  k_conv1<<<NB * NR, 256, 0, stream>>>(cnt, meta, ft, w1q, b1, g1, be1, m1, v1, x1g);
  k_conv2<<<NB * NR, 256, 0, stream>>>(cnt, x1g, w2q, b2, g2, be2, m2, v2, x2);
  k_conv3<<<NB * NR, 256, 0, stream>>>(cnt, meta, x2, wp3, g3, be3, m3, v3, out);
}

// Round 5
// 459.869 us; speedup vs baseline: 3.6117x; 1.6619x over previous
//
#include <hip/hip_runtime.h>
#include <cstddef>
#include <cstdint>

typedef unsigned short u16;
typedef __attribute__((ext_vector_type(8))) short short8;   // 8 bf16 (4 VGPRs)
typedef __attribute__((ext_vector_type(4))) float f32x4;    // 4 fp32 acc

#define NB 8
#define NR 128
#define NPOS 49
#define C1 256
#define C2 256
#define C3 32
#define EPSV 1e-5f

// d_out (fp32): er_c [8,1,128,4] | out_c [8,128,32,7,7] | keep_count [8]
#define OUT_OC   4096
#define OUT_KEEP 1609728

// workspace layout (bytes), total ~70.5 MB < proven-available 75.07 MB
static constexpr size_t OFF_META = 256;                        // cnt at 0
static constexpr size_t OFF_W1Q  = 40960;                      // bf16 frag-packed W1 (4.72 MB)
static constexpr size_t OFF_W2Q  = OFF_W1Q + 4718592;          // bf16 frag-packed W2 (1.18 MB)
static constexpr size_t OFF_W3   = OFF_W2Q + 1179648;          // f32 [256 ic][32 oc]
static constexpr size_t OFF_X1   = OFF_W3  + 32768;            // bf16 [1024 slot][4 c][49][64]
static constexpr size_t OFF_X2   = OFF_X1  + 25690112;         // bf16 [1024 slot][49][256]
static constexpr size_t OFF_S    = OFF_X2  + 25690112;         // f32 integral [8][20][20][1024]
static constexpr size_t WS_NEED  = OFF_S   + 13107200;

static __device__ __forceinline__ float bf2f(u16 v) {
  union { unsigned int u; float f; } x; x.u = ((unsigned int)v) << 16; return x.f;
}
static __device__ __forceinline__ u16 f2bf(float f) {
  union { float f; unsigned int u; } x; x.f = f;
  unsigned int r = 0x7fffu + ((x.u >> 16) & 1u);
  return (u16)((x.u + r) >> 16);
}

// ---------------- setup: ROI decode, validity, stable compaction, er_c, keep_count
__global__ void k_setup(const float* __restrict__ roi, int* __restrict__ cnt,
                        int* __restrict__ meta, float* __restrict__ out)
{
  int b = blockIdx.x, t = threadIdx.x;
  __shared__ int sval[128], spre[129];
  const float* rp = roi + (size_t)(b * NR + t) * 5;
  int rl[4], cl[4];
#pragma unroll
  for (int j = 0; j < 4; ++j) {
    rl[j] = (int)(rp[1 + j] * 18.75f);
    cl[j] = min(max(rl[j], 0), 18);
  }
  int valid = (cl[2] > cl[0]) && (cl[3] > cl[1]) ? 1 : 0;
  sval[t] = valid;
  __syncthreads();
  if (t == 0) {
    int s = 0;
    for (int i = 0; i < 128; ++i) { spre[i] = s; s += sval[i]; }
    out[OUT_KEEP + b] = (float)s;
  }
  __syncthreads();
  if (valid) {
    int dst = spre[t];
    int slot = atomicAdd(cnt, 1);
    int* mt = meta + slot * 8;
    mt[0] = b; mt[1] = dst;
    mt[2] = cl[1]; mt[3] = cl[3];
    mt[4] = cl[0]; mt[5] = cl[2];
#pragma unroll
    for (int j = 0; j < 4; ++j)
      out[(size_t)(b * NR + dst) * 4 + j] = (float)rl[j] * (16.0f / 300.0f);
  }
}

// ---------------- integral image: feat [8][1024][19][19] -> S [8][20][20][1024] (prefix sums)
__global__ void k_int(const float* __restrict__ feat, float* __restrict__ S)
{
  int g = blockIdx.x * 256 + threadIdx.x;       // 8192 threads: one per (b, ch)
  int b = g >> 10, ch = g & 1023;
  const float* fp = feat + ((size_t)b * 1024 + ch) * 361;
  float* Sp = S + (size_t)b * 400 * 1024 + ch;
  float prev[20];
#pragma unroll
  for (int w = 0; w < 20; ++w) { prev[w] = 0.f; Sp[(size_t)w * 1024] = 0.f; }
  for (int h = 0; h < 19; ++h) {
    float run = 0.f;
    float* Sr = Sp + (size_t)(h + 1) * 20 * 1024;
    Sr[0] = 0.f;
#pragma unroll
    for (int w = 0; w < 19; ++w) {
      run += fp[h * 19 + w];
      float v = run + prev[w + 1];
      Sr[(size_t)(w + 1) * 1024] = v;
      prev[w + 1] = v;
    }
  }
}

// ---------------- pack 3x3 conv weights (fp32 OIHW) into bf16 MFMA-fragment order (verified R4)
__global__ void k_pack_wq(const float* __restrict__ W, u16* __restrict__ wq, int IC) {
  int bid = blockIdx.x;                 // (c*9 + k9i)*2 + ks
  int ks = bid & 1, t2 = bid >> 1;
  int k9i = t2 % 9, c = t2 / 9;
  int ky = k9i / 3, kx = k9i - 3 * ky;
  int tid = threadIdx.x;                // 1024 = nt16*64 + lane
  int lane = tid & 63, nt16 = tid >> 6;
  int oc = nt16 * 16 + (lane & 15);
  int icb = c * 64 + ks * 32 + (lane >> 4) * 8;
  u16 v[8];
#pragma unroll
  for (int j = 0; j < 8; ++j)
    v[j] = f2bf(W[(((size_t)oc * IC + icb + j) * 3 + ky) * 3 + kx]);
  *(uint4*)(wq + ((size_t)bid * 1024 + tid) * 8) = *(uint4*)v;
}

__global__ void k_pack_w3(const float* __restrict__ in, float* __restrict__ wp) {
  int i = blockIdx.x * 256 + threadIdx.x;   // [32 oc][256 ic] -> [ic][oc]
  if (i >= C3 * C2) return;
  int oc = i / C2, ic = i - oc * C2;
  wp[ic * C3 + oc] = in[i];
}

// ================= conv1: integral-pool whole A panel to LDS once, then barrier-free MFMA
#define A1STR 1032   // row stride (bf16 elems): 1024 + 8 pad -> 4-bank rotation per row
__global__ __launch_bounds__(256) void k_conv1(
    const int* __restrict__ cnt, const int* __restrict__ meta,
    const float* __restrict__ S, const u16* __restrict__ w1q,
    const float* __restrict__ bb, const float* __restrict__ gg, const float* __restrict__ bec,
    const float* __restrict__ mm, const float* __restrict__ vv,
    u16* __restrict__ x1g)
{
  int slot = blockIdx.x;
  if (slot >= *cnt) return;
  const int* mt_ = meta + slot * 8;
  int b = mt_[0], ylo = mt_[2], yhi = mt_[3], xlo = mt_[4], xhi = mt_[5];
  int Hy = yhi - ylo + 1, Hx = xhi - xlo + 1;

  __shared__ __align__(16) u16 At[50 * A1STR];   // rows 0..48 = bins, row 49 = zeros (103 KB)
  int tid = threadIdx.x;
  // zero row 49 only (pooling fills rows 0..48 entirely; pad cols never read)
  for (int i = tid; i < A1STR / 2; i += 256) ((unsigned int*)(At + 49 * A1STR))[i] = 0;

  int lane = tid & 63, w = tid >> 6;
  int n = lane & 15, kq = lane >> 4;

  // ---- pooling via integral image: 16c * 49bin * 64ch = 50176 tasks, 4-way interleaved
  const float* Sb = S + (size_t)b * 400 * 1024;
#pragma unroll 1
  for (int t0 = tid; t0 < 50176; t0 += 1024) {
#pragma unroll
    for (int u = 0; u < 4; ++u) {
      int t = t0 + u * 256;
      int ch = t & 63, r = t >> 6;
      int bin = r % 49, c = r / 49;
      int p = bin / 7, q = bin - 7 * p;
      int sy = (p * Hy) / 7, ey = ((p + 1) * Hy + 6) / 7;
      int sx = (q * Hx) / 7, ex = ((q + 1) * Hx + 6) / 7;
      int y0 = ylo + sy, y1 = ylo + ey, x0 = xlo + sx, x1 = xlo + ex;
      const float* Sc = Sb + c * 64 + ch;
      float v = Sc[(size_t)(y1 * 20 + x1) * 1024] - Sc[(size_t)(y0 * 20 + x1) * 1024]
              - Sc[(size_t)(y1 * 20 + x0) * 1024] + Sc[(size_t)(y0 * 20 + x0) * 1024];
      v /= (float)((ey - sy) * (ex - sx));
      At[bin * A1STR + c * 64 + ch] = f2bf(v);
    }
  }

  // ---- precompute A-fragment LDS offsets: rr[mt][tap] resolved, tap-shift + padding via row 49
  int aoff[4][9];
#pragma unroll
  for (int mt = 0; mt < 4; ++mt) {
    int m = mt * 16 + n;
    int mv = m < 49;
    int mm_ = mv ? m : 0;
    int p = mm_ / 7, q = mm_ - 7 * p;
#pragma unroll
    for (int t9 = 0; t9 < 9; ++t9) {
      int ky = t9 / 3, kx = t9 - 3 * (t9 / 3);
      int ry = p + ky - 1, rx = q + kx - 1;
      int ok = mv && ry >= 0 && ry < 7 && rx >= 0 && rx < 7;
      int rr = ok ? (ry * 7 + rx) : 49;
      aoff[mt][t9] = rr * A1STR + kq * 8;
    }
  }
  f32x4 acc[4][4];
#pragma unroll
  for (int i = 0; i < 4; ++i)
#pragma unroll
    for (int j = 0; j < 4; ++j) acc[i][j] = (f32x4){0.f, 0.f, 0.f, 0.f};

  __syncthreads();   // the only barrier: A panel ready

  const u16* bw = w1q + (size_t)w * 2048 + (size_t)lane * 8;   // wave's B base
#pragma unroll 1
  for (int co = 0; co < 16; co += 4) {
    const u16* Atc = At + co * 64;
    const u16* bco = bw + (size_t)co * 18 * 8192;
#pragma unroll
    for (int c4 = 0; c4 < 4; ++c4) {
#pragma unroll
      for (int t9 = 0; t9 < 9; ++t9) {
#pragma unroll
        for (int ks = 0; ks < 2; ++ks) {
          int kk = t9 * 2 + ks;
          short8 bfr[4], afr[4];
#pragma unroll
          for (int nt = 0; nt < 4; ++nt)
            bfr[nt] = *(const short8*)(bco + (size_t)(c4 * 18 + kk) * 8192 + nt * 512);
#pragma unroll
          for (int mt = 0; mt < 4; ++mt)
            afr[mt] = *(const short8*)(Atc + aoff[mt][t9] + c4 * 64 + ks * 32);
#pragma unroll
          for (int mt = 0; mt < 4; ++mt)
#pragma unroll
            for (int nt = 0; nt < 4; ++nt)
              acc[mt][nt] = __builtin_amdgcn_mfma_f32_16x16x32_bf16(afr[mt], bfr[nt], acc[mt][nt], 0, 0, 0);
        }
      }
    }
  }
  // ---- epilogue: BN + ReLU -> x1g[slot][oc>>6][m][oc&63] bf16 (layout verified R4)
#pragma unroll
  for (int nt = 0; nt < 4; ++nt) {
    int oc = (w * 4 + nt) * 16 + n;
    float sc = gg[oc] * rsqrtf(vv[oc] + EPSV);
    float sh = (bb[oc] - mm[oc]) * sc + bec[oc];
#pragma unroll
    for (int mt = 0; mt < 4; ++mt)
#pragma unroll
      for (int r = 0; r < 4; ++r) {
        int m = mt * 16 + kq * 4 + r;
        if (m < 49) {
          float y = fmaf(acc[mt][nt][r], sc, sh);
          x1g[((size_t)(slot * 4 + w) * 49 + m) * 64 + nt * 16 + n] = f2bf(y > 0.f ? y : 0.f);
        }
      }
  }
}

// ================= conv2: stage x1 panel to LDS once, barrier-free MFMA
#define A2STR 264    // 256 + 8 pad
__global__ __launch_bounds__(256) void k_conv2(
    const int* __restrict__ cnt,
    const u16* __restrict__ x1g, const u16* __restrict__ w2q,
    const float* __restrict__ bb, const float* __restrict__ gg, const float* __restrict__ bec,
    const float* __restrict__ mm, const float* __restrict__ vv,
    u16* __restrict__ x2)
{
  int slot = blockIdx.x;
  if (slot >= *cnt) return;
  __shared__ __align__(16) u16 At[50 * A2STR];   // 26.4 KB
  int tid = threadIdx.x;
  for (int i = tid; i < A2STR / 2; i += 256) ((unsigned int*)(At + 49 * A2STR))[i] = 0;
  // stage rows 0..48: 49 * 32 uint4
  const u16* xs = x1g + (size_t)slot * 4 * 49 * 64;
#pragma unroll 1
  for (int t = tid; t < 49 * 32; t += 256) {
    int row = t >> 5, j = t & 31;
    uint4 v = *(const uint4*)(xs + ((size_t)(j >> 3) * 49 + row) * 64 + (j & 7) * 8);
    *(uint4*)(At + row * A2STR + j * 8) = v;
  }

  int lane = tid & 63, w = tid >> 6;
  int n = lane & 15, kq = lane >> 4;
  int aoff[4][9];
#pragma unroll
  for (int mt = 0; mt < 4; ++mt) {
    int m = mt * 16 + n;
    int mv = m < 49;
    int mm_ = mv ? m : 0;
    int p = mm_ / 7, q = mm_ - 7 * p;
#pragma unroll
    for (int t9 = 0; t9 < 9; ++t9) {
      int ky = t9 / 3, kx = t9 - 3 * (t9 / 3);
      int ry = p + ky - 1, rx = q + kx - 1;
      int ok = mv && ry >= 0 && ry < 7 && rx >= 0 && rx < 7;
      int rr = ok ? (ry * 7 + rx) : 49;
      aoff[mt][t9] = rr * A2STR + kq * 8;
    }
  }
  f32x4 acc[4][4];
#pragma unroll
  for (int i = 0; i < 4; ++i)
#pragma unroll
    for (int j = 0; j < 4; ++j) acc[i][j] = (f32x4){0.f, 0.f, 0.f, 0.f};

  __syncthreads();

  const u16* bw = w2q + (size_t)w * 2048 + (size_t)lane * 8;
#pragma unroll 1
  for (int c = 0; c < 4; ++c) {
#pragma unroll
    for (int t9 = 0; t9 < 9; ++t9) {
#pragma unroll
      for (int ks = 0; ks < 2; ++ks) {
        int kk = t9 * 2 + ks;
        short8 bfr[4], afr[4];
#pragma unroll
        for (int nt = 0; nt < 4; ++nt)
          bfr[nt] = *(const short8*)(bw + (size_t)(c * 18 + kk) * 8192 + nt * 512);
#pragma unroll
        for (int mt = 0; mt < 4; ++mt)
          afr[mt] = *(const short8*)(At + aoff[mt][t9] + c * 64 + ks * 32);
#pragma unroll
        for (int mt = 0; mt < 4; ++mt)
#pragma unroll
          for (int nt = 0; nt < 4; ++nt)
            acc[mt][nt] = __builtin_amdgcn_mfma_f32_16x16x32_bf16(afr[mt], bfr[nt], acc[mt][nt], 0, 0, 0);
      }
    }
  }
#pragma unroll
  for (int nt = 0; nt < 4; ++nt) {
    int oc = (w * 4 + nt) * 16 + n;
    float sc = gg[oc] * rsqrtf(vv[oc] + EPSV);
    float sh = (bb[oc] - mm[oc]) * sc + bec[oc];
#pragma unroll
    for (int mt = 0; mt < 4; ++mt)
#pragma unroll
      for (int r = 0; r < 4; ++r) {
        int m = mt * 16 + kq * 4 + r;
        if (m < 49) {
          float y = fmaf(acc[mt][nt][r], sc, sh);
          x2[((size_t)slot * 49 + m) * 256 + oc] = f2bf(y > 0.f ? y : 0.f);
        }
      }
  }
}

// ---------------- conv3 (1x1) + BN + ReLU + scatter to compacted out_c
__global__ __launch_bounds__(256) void k_conv3(
    const int* __restrict__ cnt, const int* __restrict__ meta,
    const u16* __restrict__ x2, const float* __restrict__ wp3,
    const float* __restrict__ gg, const float* __restrict__ bec,
    const float* __restrict__ mm, const float* __restrict__ vv,
    float* __restrict__ out)
{
  int slot = blockIdx.x;
  if (slot >= *cnt) return;
  const int* mt = meta + slot * 8;
  int b = mt[0], dst = mt[1];
  __shared__ float t3[NPOS * C2];               // [pos][ic], 50 KB
  int tid = threadIdx.x;
  const u16* xp = x2 + (size_t)slot * NPOS * C2;
#pragma unroll 1
  for (int i = tid; i < NPOS * C2 / 8; i += 256) {
    uint4 v = ((const uint4*)xp)[i];
    u16* h = (u16*)&v;
#pragma unroll
    for (int j = 0; j < 8; ++j) t3[i * 8 + j] = bf2f(h[j]);
  }
  __syncthreads();
  int oc = tid & 31, pg = tid >> 5;
  float acc[7];
#pragma unroll
  for (int j = 0; j < 7; ++j) acc[j] = 0.f;
  for (int ic = 0; ic < C2; ++ic) {
    float wv = wp3[ic * 32 + oc];
#pragma unroll
    for (int j = 0; j < 7; ++j) {
      int p = pg + j * 8;
      if (p < NPOS) acc[j] = fmaf(t3[p * C2 + ic], wv, acc[j]);
    }
  }
  float sc = gg[oc] * rsqrtf(vv[oc] + EPSV);
  float sh = bec[oc] - mm[oc] * sc;
  size_t obase = OUT_OC + ((size_t)(b * NR + dst) * C3 + oc) * NPOS;
#pragma unroll
  for (int j = 0; j < 7; ++j) {
    int p = pg + j * 8;
    if (p < NPOS) {
      float y = fmaf(acc[j], sc, sh);
      out[obase + p] = y > 0.f ? y : 0.f;
    }
  }
}

extern "C" void kernel_launch(void* const* d_in, const int* in_sizes, int n_in,
                              void* d_out, int out_size, void* d_ws, size_t ws_size,
                              hipStream_t stream)
{
  (void)in_sizes; (void)n_in;
  if (ws_size < WS_NEED) return;

  const float* roi  = (const float*)d_in[0];
  const float* feat = (const float*)d_in[1];
  const float* W1   = (const float*)d_in[2];
  const float* b1   = (const float*)d_in[3];
  const float* g1   = (const float*)d_in[4];
  const float* be1  = (const float*)d_in[5];
  const float* m1   = (const float*)d_in[6];
  const float* v1   = (const float*)d_in[7];
  const float* W2   = (const float*)d_in[8];
  const float* b2   = (const float*)d_in[9];
  const float* g2   = (const float*)d_in[10];
  const float* be2  = (const float*)d_in[11];
  const float* m2   = (const float*)d_in[12];
  const float* v2   = (const float*)d_in[13];
  const float* W3   = (const float*)d_in[14];
  const float* g3   = (const float*)d_in[15];
  const float* be3  = (const float*)d_in[16];
  const float* m3   = (const float*)d_in[17];
  const float* v3   = (const float*)d_in[18];

  char* ws   = (char*)d_ws;
  int*  cnt  = (int*)ws;
  int*  meta = (int*)(ws + OFF_META);
  u16*  w1q  = (u16*)(ws + OFF_W1Q);
  u16*  w2q  = (u16*)(ws + OFF_W2Q);
  float* wp3 = (float*)(ws + OFF_W3);
  u16*  x1g  = (u16*)(ws + OFF_X1);
  u16*  x2   = (u16*)(ws + OFF_X2);
  float* S   = (float*)(ws + OFF_S);
  float* out = (float*)d_out;

  hipMemsetAsync(cnt, 0, 4, stream);
  hipMemsetAsync(d_out, 0, (size_t)out_size * sizeof(float), stream);

  k_int<<<32, 256, 0, stream>>>(feat, S);
  k_pack_wq<<<16 * 9 * 2, 1024, 0, stream>>>(W1, w1q, 1024);
  k_pack_wq<<<4 * 9 * 2, 1024, 0, stream>>>(W2, w2q, 256);
  k_pack_w3<<<(C3 * C2 + 255) / 256, 256, 0, stream>>>(W3, wp3);
  k_setup<<<NB, NR, 0, stream>>>(roi, cnt, meta, out);

  k_conv1<<<NB * NR, 256, 0, stream>>>(cnt, meta, S, w1q, b1, g1, be1, m1, v1, x1g);
  k_conv2<<<NB * NR, 256, 0, stream>>>(cnt, x1g, w2q, b2, g2, be2, m2, v2, x2);
  k_conv3<<<NB * NR, 256, 0, stream>>>(cnt, meta, x2, wp3, g3, be3, m3, v3, out);
}

// Round 6
// 326.311 us; speedup vs baseline: 5.0899x; 1.4093x over previous
//
#include <hip/hip_runtime.h>
#include <cstddef>
#include <cstdint>

typedef unsigned short u16;
typedef __attribute__((ext_vector_type(8))) short short8;   // 8 bf16 (4 VGPRs)
typedef __attribute__((ext_vector_type(4))) float f32x4;    // 4 fp32 acc

#define NB 8
#define NR 128
#define NPOS 49
#define C1 256
#define C2 256
#define C3 32
#define EPSV 1e-5f

// d_out (fp32): er_c [8,1,128,4] | out_c [8,128,32,7,7] | keep_count [8]
#define OUT_OC   4096
#define OUT_KEEP 1609728

// workspace layout (bytes), total ~70.5 MB < proven-available 75.07 MB
static constexpr size_t OFF_META = 256;                        // cnt at 0
static constexpr size_t OFF_W1Q  = 40960;                      // bf16 frag-packed W1 (4.72 MB)
static constexpr size_t OFF_W2Q  = OFF_W1Q + 4718592;          // bf16 frag-packed W2 (1.18 MB)
static constexpr size_t OFF_W3   = OFF_W2Q + 1179648;          // f32 [256 ic][32 oc]
static constexpr size_t OFF_X1   = OFF_W3  + 32768;            // bf16 [1024 slot][4 c][49][64]
static constexpr size_t OFF_X2   = OFF_X1  + 25690112;         // bf16 [1024 slot][49][256]
static constexpr size_t OFF_S    = OFF_X2  + 25690112;         // f32 integral [8][20][20][1024]
static constexpr size_t WS_NEED  = OFF_S   + 13107200;

static __device__ __forceinline__ float bf2f(u16 v) {
  union { unsigned int u; float f; } x; x.u = ((unsigned int)v) << 16; return x.f;
}
static __device__ __forceinline__ u16 f2bf(float f) {
  union { float f; unsigned int u; } x; x.f = f;
  unsigned int r = 0x7fffu + ((x.u >> 16) & 1u);
  return (u16)((x.u + r) >> 16);
}

// ---------------- setup: ROI decode, validity, stable compaction, er_c, keep_count
__global__ void k_setup(const float* __restrict__ roi, int* __restrict__ cnt,
                        int* __restrict__ meta, float* __restrict__ out)
{
  int b = blockIdx.x, t = threadIdx.x;
  __shared__ int sval[128], spre[129];
  const float* rp = roi + (size_t)(b * NR + t) * 5;
  int rl[4], cl[4];
#pragma unroll
  for (int j = 0; j < 4; ++j) {
    rl[j] = (int)(rp[1 + j] * 18.75f);
    cl[j] = min(max(rl[j], 0), 18);
  }
  int valid = (cl[2] > cl[0]) && (cl[3] > cl[1]) ? 1 : 0;
  sval[t] = valid;
  __syncthreads();
  if (t == 0) {
    int s = 0;
    for (int i = 0; i < 128; ++i) { spre[i] = s; s += sval[i]; }
    out[OUT_KEEP + b] = (float)s;
  }
  __syncthreads();
  if (valid) {
    int dst = spre[t];
    int slot = atomicAdd(cnt, 1);
    int* mt = meta + slot * 8;
    mt[0] = b; mt[1] = dst;
    mt[2] = cl[1]; mt[3] = cl[3];
    mt[4] = cl[0]; mt[5] = cl[2];
#pragma unroll
    for (int j = 0; j < 4; ++j)
      out[(size_t)(b * NR + dst) * 4 + j] = (float)rl[j] * (16.0f / 300.0f);
  }
}

// ---------------- integral image, coalesced: feat [8][1024][19][19] -> S [8][20][20][1024]
__global__ __launch_bounds__(256) void k_int(const float* __restrict__ feat, float* __restrict__ S)
{
  int b = blockIdx.x, cg = blockIdx.y;          // 8 x 16 blocks, 64 channels each
  __shared__ float F[64 * 361];                 // 92.4 KB
  int tid = threadIdx.x;
  const float* fb = feat + ((size_t)b * 1024 + cg * 64) * 361;
#pragma unroll 1
  for (int i = tid; i < 64 * 361; i += 256) F[i] = fb[i];   // coalesced
  __syncthreads();
  if (tid < 64) {
    int ch = tid;
    const float* fp = F + ch * 361;
    float* Sp = S + (size_t)b * 400 * 1024 + cg * 64 + ch;
    float prev[20];
#pragma unroll
    for (int w = 0; w < 20; ++w) { prev[w] = 0.f; Sp[(size_t)w * 1024] = 0.f; }
    for (int h = 0; h < 19; ++h) {
      float run = 0.f;
      float* Sr = Sp + (size_t)(h + 1) * 20 * 1024;
      Sr[0] = 0.f;
#pragma unroll
      for (int w = 0; w < 19; ++w) {
        run += fp[h * 19 + w];
        float v = run + prev[w + 1];
        Sr[(size_t)(w + 1) * 1024] = v;
        prev[w + 1] = v;
      }
    }
  }
}

// ---------------- pack 3x3 weights, elementwise (coalesced read, scattered 2B write)
// dst layout (verified R4/R5): elem = (bid_*1024 + nt16*64 + lane)*8 + j
__global__ void k_pack_wq(const float* __restrict__ W, u16* __restrict__ wq, int IC, int N) {
  int i = blockIdx.x * 256 + threadIdx.x;
  if (i >= N) return;
  float v = W[i];
  int kx = i % 3; int t = i / 3; int ky = t % 3; int t2 = t / 3;
  int ic = t2 % IC; int oc = t2 / IC;
  int k9i = ky * 3 + kx; int c = ic >> 6; int ks = (ic >> 5) & 1;
  int bid_ = (c * 9 + k9i) * 2 + ks;
  int lane = ((ic >> 3) & 3) * 16 + (oc & 15);
  int nt16 = oc >> 4;
  int j = ic & 7;
  wq[((size_t)bid_ * 1024 + nt16 * 64 + lane) * 8 + j] = f2bf(v);
}

__global__ void k_pack_w3(const float* __restrict__ in, float* __restrict__ wp) {
  int i = blockIdx.x * 256 + threadIdx.x;   // [32 oc][256 ic] -> [ic][oc]
  if (i >= C3 * C2) return;
  int oc = i / C2, ic = i - oc * C2;
  wp[ic * C3 + oc] = in[i];
}

// ================= conv1: pool panel to LDS once; 8 waves = 4 oc-groups x 2 K-halves;
// barrier-free MFMA loop with distance-2 register prefetch of B; LDS K-reduction.
#define A1STR 1032   // row stride (bf16): 1024 + 8 pad
__global__ __launch_bounds__(512) void k_conv1(
    const int* __restrict__ cnt, const int* __restrict__ meta,
    const float* __restrict__ S, const u16* __restrict__ w1q,
    const float* __restrict__ bb, const float* __restrict__ gg, const float* __restrict__ bec,
    const float* __restrict__ mm, const float* __restrict__ vv,
    u16* __restrict__ x1g)
{
  int slot = blockIdx.x;
  if (slot >= *cnt) return;
  const int* mt_ = meta + slot * 8;
  int b = mt_[0], ylo = mt_[2], yhi = mt_[3], xlo = mt_[4], xhi = mt_[5];
  int Hy = yhi - ylo + 1, Hx = xhi - xlo + 1;

  __shared__ __align__(16) char smem[50 * A1STR * 2];   // 103.2 KB: A panel, later aliased by red
  u16* At = (u16*)smem;
  float* red = (float*)smem;                            // 4*49*64 f32 = 50 KB, alias (At dead)

  int tid = threadIdx.x;
  for (int i = tid; i < A1STR / 2; i += 512) ((unsigned int*)(At + 49 * A1STR))[i] = 0;

  int lane = tid & 63, wave = tid >> 6;
  int wo = wave & 3, wk = wave >> 2;        // oc-group, K-half
  int n = lane & 15, kq = lane >> 4;

  // ---- pooling via integral image: 16c * 49bin * 64ch tasks, cooperative
  const float* Sb = S + (size_t)b * 400 * 1024;
#pragma unroll 1
  for (int t0 = tid; t0 < 50176; t0 += 2048) {
#pragma unroll
    for (int u = 0; u < 4; ++u) {
      int t = t0 + u * 512;
      if (t < 50176) {
        int ch = t & 63, r = t >> 6;
        int bin = r % 49, c = r / 49;
        int p = bin / 7, q = bin - 7 * p;
        int sy = (p * Hy) / 7, ey = ((p + 1) * Hy + 6) / 7;
        int sx = (q * Hx) / 7, ex = ((q + 1) * Hx + 6) / 7;
        int y0 = ylo + sy, y1 = ylo + ey, x0 = xlo + sx, x1 = xlo + ex;
        const float* Sc = Sb + c * 64 + ch;
        float v = Sc[(size_t)(y1 * 20 + x1) * 1024] - Sc[(size_t)(y0 * 20 + x1) * 1024]
                - Sc[(size_t)(y1 * 20 + x0) * 1024] + Sc[(size_t)(y0 * 20 + x0) * 1024];
        v /= (float)((ey - sy) * (ex - sx));
        At[bin * A1STR + c * 64 + ch] = f2bf(v);
      }
    }
  }

  // ---- A-fragment LDS offsets (tap-shift + zero-pad resolved via row 49)
  int aoff[4][9];
#pragma unroll
  for (int mt = 0; mt < 4; ++mt) {
    int m = mt * 16 + n;
    int mv = m < 49;
    int mm2 = mv ? m : 0;
    int p = mm2 / 7, q = mm2 - 7 * p;
#pragma unroll
    for (int t9 = 0; t9 < 9; ++t9) {
      int ky = t9 / 3, kx = t9 - 3 * (t9 / 3);
      int ry = p + ky - 1, rx = q + kx - 1;
      int ok = mv && ry >= 0 && ry < 7 && rx >= 0 && rx < 7;
      int rr = ok ? (ry * 7 + rx) : 49;
      aoff[mt][t9] = rr * A1STR + kq * 8;
    }
  }
  f32x4 acc[4][4];
#pragma unroll
  for (int i = 0; i < 4; ++i)
#pragma unroll
    for (int j = 0; j < 4; ++j) acc[i][j] = (f32x4){0.f, 0.f, 0.f, 0.f};

  // wave's B base: nt16_global = wo*4 + nt
  const u16* bw = w1q + (size_t)wo * 4 * 512 + (size_t)lane * 8;
  int c0 = wk * 8;
  short8 bbuf[2][4];
#pragma unroll
  for (int nt = 0; nt < 4; ++nt) {
    bbuf[0][nt] = *(const short8*)(bw + (size_t)c0 * 147456 + 0 * 8192 + nt * 512);
    bbuf[1][nt] = *(const short8*)(bw + (size_t)c0 * 147456 + 1 * 8192 + nt * 512);
  }

  __syncthreads();   // A panel ready

#pragma unroll 1
  for (int c8 = 0; c8 < 8; ++c8) {
    int c = c0 + c8;
    const u16* Atc = At + c * 64;
    const u16* bc = bw + (size_t)c * 147456;
#pragma unroll
    for (int kk = 0; kk < 18; ++kk) {
      int t9 = kk >> 1, ks = kk & 1;
      short8 bfr[4];
#pragma unroll
      for (int nt = 0; nt < 4; ++nt) bfr[nt] = bbuf[kk & 1][nt];
      // prefetch step kk+2 (wraps harmlessly at the tail)
      int pc8 = c8, pk = kk + 2;
      if (pk >= 18) { pk -= 18; pc8 = (c8 < 7) ? c8 + 1 : 0; }
      const u16* bp = bw + (size_t)(c0 + pc8) * 147456 + (size_t)pk * 8192;
#pragma unroll
      for (int nt = 0; nt < 4; ++nt) bbuf[kk & 1][nt] = *(const short8*)(bp + nt * 512);
      short8 afr[4];
#pragma unroll
      for (int mt = 0; mt < 4; ++mt)
        afr[mt] = *(const short8*)(Atc + aoff[mt][t9] + ks * 32);
#pragma unroll
      for (int mt = 0; mt < 4; ++mt)
#pragma unroll
        for (int nt = 0; nt < 4; ++nt)
          acc[mt][nt] = __builtin_amdgcn_mfma_f32_16x16x32_bf16(afr[mt], bfr[nt], acc[mt][nt], 0, 0, 0);
    }
  }

  __syncthreads();   // all waves done reading At -> red may alias it
  if (wk == 1) {
#pragma unroll
    for (int nt = 0; nt < 4; ++nt)
#pragma unroll
      for (int mt = 0; mt < 4; ++mt)
#pragma unroll
        for (int r = 0; r < 4; ++r) {
          int m = mt * 16 + kq * 4 + r;
          if (m < 49) red[((size_t)wo * 49 + m) * 64 + nt * 16 + n] = acc[mt][nt][r];
        }
  }
  __syncthreads();
  if (wk == 0) {
#pragma unroll
    for (int nt = 0; nt < 4; ++nt) {
      int oc = wo * 64 + nt * 16 + n;
      float sc = gg[oc] * rsqrtf(vv[oc] + EPSV);
      float sh = (bb[oc] - mm[oc]) * sc + bec[oc];
#pragma unroll
      for (int mt = 0; mt < 4; ++mt)
#pragma unroll
        for (int r = 0; r < 4; ++r) {
          int m = mt * 16 + kq * 4 + r;
          if (m < 49) {
            float y = acc[mt][nt][r] + red[((size_t)wo * 49 + m) * 64 + nt * 16 + n];
            y = fmaf(y, sc, sh);
            x1g[((size_t)(slot * 4 + wo) * 49 + m) * 64 + nt * 16 + n] = f2bf(y > 0.f ? y : 0.f);
          }
        }
    }
  }
}

// ================= conv2: same skeleton, K=1024 over 4 c-chunks, 2 K-halves of 2c
#define A2STR 264    // 256 + 8 pad
__global__ __launch_bounds__(512) void k_conv2(
    const int* __restrict__ cnt,
    const u16* __restrict__ x1g, const u16* __restrict__ w2q,
    const float* __restrict__ bb, const float* __restrict__ gg, const float* __restrict__ bec,
    const float* __restrict__ mm, const float* __restrict__ vv,
    u16* __restrict__ x2)
{
  int slot = blockIdx.x;
  if (slot >= *cnt) return;
  __shared__ __align__(16) char smem[50176];   // max(A panel 26.4 KB, red 50 KB)
  u16* At = (u16*)smem;
  float* red = (float*)smem;

  int tid = threadIdx.x;
  for (int i = tid; i < A2STR / 2; i += 512) ((unsigned int*)(At + 49 * A2STR))[i] = 0;
  const u16* xs = x1g + (size_t)slot * 4 * 49 * 64;
#pragma unroll 1
  for (int t = tid; t < 49 * 32; t += 512) {
    int row = t >> 5, j = t & 31;
    uint4 v = *(const uint4*)(xs + ((size_t)(j >> 3) * 49 + row) * 64 + (j & 7) * 8);
    *(uint4*)(At + row * A2STR + j * 8) = v;
  }

  int lane = tid & 63, wave = tid >> 6;
  int wo = wave & 3, wk = wave >> 2;
  int n = lane & 15, kq = lane >> 4;
  int aoff[4][9];
#pragma unroll
  for (int mt = 0; mt < 4; ++mt) {
    int m = mt * 16 + n;
    int mv = m < 49;
    int mm2 = mv ? m : 0;
    int p = mm2 / 7, q = mm2 - 7 * p;
#pragma unroll
    for (int t9 = 0; t9 < 9; ++t9) {
      int ky = t9 / 3, kx = t9 - 3 * (t9 / 3);
      int ry = p + ky - 1, rx = q + kx - 1;
      int ok = mv && ry >= 0 && ry < 7 && rx >= 0 && rx < 7;
      int rr = ok ? (ry * 7 + rx) : 49;
      aoff[mt][t9] = rr * A2STR + kq * 8;
    }
  }
  f32x4 acc[4][4];
#pragma unroll
  for (int i = 0; i < 4; ++i)
#pragma unroll
    for (int j = 0; j < 4; ++j) acc[i][j] = (f32x4){0.f, 0.f, 0.f, 0.f};

  const u16* bw = w2q + (size_t)wo * 4 * 512 + (size_t)lane * 8;
  int c0 = wk * 2;
  short8 bbuf[2][4];
#pragma unroll
  for (int nt = 0; nt < 4; ++nt) {
    bbuf[0][nt] = *(const short8*)(bw + (size_t)c0 * 147456 + 0 * 8192 + nt * 512);
    bbuf[1][nt] = *(const short8*)(bw + (size_t)c0 * 147456 + 1 * 8192 + nt * 512);
  }

  __syncthreads();

#pragma unroll 1
  for (int c2 = 0; c2 < 2; ++c2) {
    int c = c0 + c2;
    const u16* Atc = At + c * 64;
#pragma unroll
    for (int kk = 0; kk < 18; ++kk) {
      int t9 = kk >> 1, ks = kk & 1;
      short8 bfr[4];
#pragma unroll
      for (int nt = 0; nt < 4; ++nt) bfr[nt] = bbuf[kk & 1][nt];
      int pc2 = c2, pk = kk + 2;
      if (pk >= 18) { pk -= 18; pc2 = (c2 < 1) ? c2 + 1 : 0; }
      const u16* bp = bw + (size_t)(c0 + pc2) * 147456 + (size_t)pk * 8192;
#pragma unroll
      for (int nt = 0; nt < 4; ++nt) bbuf[kk & 1][nt] = *(const short8*)(bp + nt * 512);
      short8 afr[4];
#pragma unroll
      for (int mt = 0; mt < 4; ++mt)
        afr[mt] = *(const short8*)(Atc + aoff[mt][t9] + ks * 32);
#pragma unroll
      for (int mt = 0; mt < 4; ++mt)
#pragma unroll
        for (int nt = 0; nt < 4; ++nt)
          acc[mt][nt] = __builtin_amdgcn_mfma_f32_16x16x32_bf16(afr[mt], bfr[nt], acc[mt][nt], 0, 0, 0);
    }
  }

  __syncthreads();
  if (wk == 1) {
#pragma unroll
    for (int nt = 0; nt < 4; ++nt)
#pragma unroll
      for (int mt = 0; mt < 4; ++mt)
#pragma unroll
        for (int r = 0; r < 4; ++r) {
          int m = mt * 16 + kq * 4 + r;
          if (m < 49) red[((size_t)wo * 49 + m) * 64 + nt * 16 + n] = acc[mt][nt][r];
        }
  }
  __syncthreads();
  if (wk == 0) {
#pragma unroll
    for (int nt = 0; nt < 4; ++nt) {
      int oc = wo * 64 + nt * 16 + n;
      float sc = gg[oc] * rsqrtf(vv[oc] + EPSV);
      float sh = (bb[oc] - mm[oc]) * sc + bec[oc];
#pragma unroll
      for (int mt = 0; mt < 4; ++mt)
#pragma unroll
        for (int r = 0; r < 4; ++r) {
          int m = mt * 16 + kq * 4 + r;
          if (m < 49) {
            float y = acc[mt][nt][r] + red[((size_t)wo * 49 + m) * 64 + nt * 16 + n];
            y = fmaf(y, sc, sh);
            x2[((size_t)slot * 49 + m) * 256 + oc] = f2bf(y > 0.f ? y : 0.f);
          }
        }
    }
  }
}

// ---------------- conv3 (1x1) + BN + ReLU + scatter to compacted out_c
#define T3STR 260
__global__ __launch_bounds__(256) void k_conv3(
    const int* __restrict__ cnt, const int* __restrict__ meta,
    const u16* __restrict__ x2, const float* __restrict__ wp3,
    const float* __restrict__ gg, const float* __restrict__ bec,
    const float* __restrict__ mm, const float* __restrict__ vv,
    float* __restrict__ out)
{
  int slot = blockIdx.x;
  if (slot >= *cnt) return;
  const int* mt = meta + slot * 8;
  int b = mt[0], dst = mt[1];
  __shared__ float t3[NPOS * T3STR];            // padded: conflict-free across pg
  __shared__ float w3s[C2 * C3];                // 32 KB
  int tid = threadIdx.x;
  const u16* xp = x2 + (size_t)slot * NPOS * C2;
#pragma unroll 1
  for (int i = tid; i < NPOS * C2 / 8; i += 256) {
    uint4 v = ((const uint4*)xp)[i];
    u16* h = (u16*)&v;
    int e = i * 8, pos = e >> 8, ic0 = e & 255;
    float* d = t3 + pos * T3STR + ic0;
#pragma unroll
    for (int j = 0; j < 8; ++j) d[j] = bf2f(h[j]);
  }
#pragma unroll 1
  for (int i = tid; i < C2 * C3; i += 256) w3s[i] = wp3[i];
  __syncthreads();
  int oc = tid & 31, pg = tid >> 5;
  float acc[7];
#pragma unroll
  for (int j = 0; j < 7; ++j) acc[j] = 0.f;
#pragma unroll 4
  for (int ic = 0; ic < C2; ++ic) {
    float wv = w3s[ic * 32 + oc];
#pragma unroll
    for (int j = 0; j < 7; ++j) {
      int p = pg + j * 8;
      if (p < NPOS) acc[j] = fmaf(t3[p * T3STR + ic], wv, acc[j]);
    }
  }
  float sc = gg[oc] * rsqrtf(vv[oc] + EPSV);
  float sh = bec[oc] - mm[oc] * sc;
  size_t obase = OUT_OC + ((size_t)(b * NR + dst) * C3 + oc) * NPOS;
#pragma unroll
  for (int j = 0; j < 7; ++j) {
    int p = pg + j * 8;
    if (p < NPOS) {
      float y = fmaf(acc[j], sc, sh);
      out[obase + p] = y > 0.f ? y : 0.f;
    }
  }
}

extern "C" void kernel_launch(void* const* d_in, const int* in_sizes, int n_in,
                              void* d_out, int out_size, void* d_ws, size_t ws_size,
                              hipStream_t stream)
{
  (void)in_sizes; (void)n_in;
  if (ws_size < WS_NEED) return;

  const float* roi  = (const float*)d_in[0];
  const float* feat = (const float*)d_in[1];
  const float* W1   = (const float*)d_in[2];
  const float* b1   = (const float*)d_in[3];
  const float* g1   = (const float*)d_in[4];
  const float* be1  = (const float*)d_in[5];
  const float* m1   = (const float*)d_in[6];
  const float* v1   = (const float*)d_in[7];
  const float* W2   = (const float*)d_in[8];
  const float* b2   = (const float*)d_in[9];
  const float* g2   = (const float*)d_in[10];
  const float* be2  = (const float*)d_in[11];
  const float* m2   = (const float*)d_in[12];
  const float* v2   = (const float*)d_in[13];
  const float* W3   = (const float*)d_in[14];
  const float* g3   = (const float*)d_in[15];
  const float* be3  = (const float*)d_in[16];
  const float* m3   = (const float*)d_in[17];
  const float* v3   = (const float*)d_in[18];

  char* ws   = (char*)d_ws;
  int*  cnt  = (int*)ws;
  int*  meta = (int*)(ws + OFF_META);
  u16*  w1q  = (u16*)(ws + OFF_W1Q);
  u16*  w2q  = (u16*)(ws + OFF_W2Q);
  float* wp3 = (float*)(ws + OFF_W3);
  u16*  x1g  = (u16*)(ws + OFF_X1);
  u16*  x2   = (u16*)(ws + OFF_X2);
  float* S   = (float*)(ws + OFF_S);
  float* out = (float*)d_out;

  hipMemsetAsync(cnt, 0, 4, stream);
  hipMemsetAsync(d_out, 0, (size_t)out_size * sizeof(float), stream);

  k_int<<<dim3(NB, 16), 256, 0, stream>>>(feat, S);
  k_pack_wq<<<(2359296 + 255) / 256, 256, 0, stream>>>(W1, w1q, 1024, 2359296);
  k_pack_wq<<<(589824 + 255) / 256, 256, 0, stream>>>(W2, w2q, 256, 589824);
  k_pack_w3<<<(C3 * C2 + 255) / 256, 256, 0, stream>>>(W3, wp3);
  k_setup<<<NB, NR, 0, stream>>>(roi, cnt, meta, out);

  k_conv1<<<NB * NR, 512, 0, stream>>>(cnt, meta, S, w1q, b1, g1, be1, m1, v1, x1g);
  k_conv2<<<NB * NR, 512, 0, stream>>>(cnt, x1g, w2q, b2, g2, be2, m2, v2, x2);
  k_conv3<<<NB * NR, 256, 0, stream>>>(cnt, meta, x2, wp3, g3, be3, m3, v3, out);
}